// Round 1
// baseline (24141.798 us; speedup 1.0000x reference)
//
#include <hip/hip_runtime.h>

// GeneratorDecoder: 128-step LSTM (H=32) + gumbel-argmax head (P=7), B=32768.
// 4 lanes per batch element, gate rows interleaved mod 4 (lane q owns rows
// r == q (mod 4) in each of the i/f/g/o blocks -> fully-local elementwise).
// h replicated via per-batch LDS buffer; intra-wave lockstep -> no barriers
// in the main loop. One-hot y => W_ih is a column gather (col 7 = bias-only
// for the y0=0 step). samples = one_hot(argmax(logits+gumbel)) exactly.

#define Hh 32
#define Pp 7
#define NDd 8
#define G4 128          // 4*H
#define WHH_S 40        // pad 32->40: consecutive rows differ by 8 banks, 16B aligned
#define HBUF_S 36       // pad 32->36: 2-way bank aliasing only (free)

__global__ __launch_bounds__(256, 2) void gen_decoder_kernel(
    const float* __restrict__ h_n, const float* __restrict__ c_n,
    const float* __restrict__ noise, const float* __restrict__ gumbel_u,
    const float* __restrict__ W_init, const float* __restrict__ b_init,
    const float* __restrict__ W_ih, const float* __restrict__ W_hh,
    const float* __restrict__ b_ih, const float* __restrict__ b_hh,
    const float* __restrict__ W_head, const float* __restrict__ b_head,
    const int* __restrict__ future_len, float* __restrict__ out, int B)
{
  __shared__ __align__(16) float sWhh[G4 * WHH_S];
  __shared__ __align__(16) float sWihB[G4 * 8];   // [r][p], p<7: W_ih+b_ih+b_hh; p==7: bias only
  __shared__ __align__(16) float sWheadT[Hh * 8]; // [j][p], col 7 = 0
  __shared__ __align__(16) float sWinit[Hh * (Hh + NDd)];
  __shared__ float sBinit[Hh];
  __shared__ __align__(16) float sHbuf[64 * HBUF_S];

  const int tid = threadIdx.x;

  for (int i = tid; i < G4 * Hh; i += 256) {
    int r = i >> 5, k = i & 31;
    sWhh[r * WHH_S + k] = W_hh[i];
  }
  for (int i = tid; i < G4 * 8; i += 256) {
    int r = i >> 3, p = i & 7;
    sWihB[i] = b_ih[r] + b_hh[r] + (p < 7 ? W_ih[r * 7 + p] : 0.f);
  }
  for (int i = tid; i < Hh * 8; i += 256) {
    int j = i >> 3, p = i & 7;
    sWheadT[i] = (p < 7) ? W_head[p * Hh + j] : 0.f;
  }
  for (int i = tid; i < Hh * (Hh + NDd); i += 256) sWinit[i] = W_init[i];
  if (tid < Hh) sBinit[tid] = b_init[tid];
  __syncthreads();

  const int q  = tid & 3;        // lane-in-quad: owns state slots j == q (mod 4)
  const int bb = tid >> 2;       // batch-in-block (0..63)
  const int b  = blockIdx.x * 64 + bb;
  const int T  = future_len[0];

  // ---- init: h0 = [h_n ; noise] @ W_init.T + b_init ----
  float x[Hh + NDd];
  {
    const float4* hp = (const float4*)(h_n + (size_t)b * Hh);
#pragma unroll
    for (int i = 0; i < 8; i++) ((float4*)x)[i] = hp[i];
    const float4* nz = (const float4*)(noise + (size_t)b * NDd);
    ((float4*)x)[8] = nz[0];
    ((float4*)x)[9] = nz[1];
  }
#pragma unroll
  for (int m = 0; m < 8; m++) {
    int j = q + 4 * m;
    float a = sBinit[j];
    const float* wr = &sWinit[j * (Hh + NDd)];
#pragma unroll
    for (int k = 0; k < Hh + NDd; k++) a = fmaf(wr[k], x[k], a);
    sHbuf[bb * HBUF_S + j] = a;
  }
  float c[8];
#pragma unroll
  for (int m = 0; m < 8; m++) c[m] = c_n[(size_t)b * Hh + q + 4 * m];

  float bh[Pp];
#pragma unroll
  for (int p = 0; p < Pp; p++) bh[p] = b_head[p];

  int kcur = 7;  // y0 = 0 -> bias-only column
  const size_t strideT = (size_t)B * Pp;
  const float* gu = gumbel_u + (size_t)b * Pp;
  float* outL = out + (size_t)b * T * Pp;
  float* outS = out + (size_t)B * T * Pp + (size_t)b * T * Pp;

  for (int t = 0; t < T; ++t) {
    // full replicated h (ds_read_b128 x8, written by this quad last step)
    float h[Hh];
#pragma unroll
    for (int i = 0; i < 8; i++)
      ((float4*)h)[i] = ((const float4*)&sHbuf[bb * HBUF_S])[i];

    // gates: lane q computes rows s*32 + q + 4m  (s=gate block, m=slot)
    float accs[4][8];
#pragma unroll
    for (int s = 0; s < 4; s++) {
#pragma unroll
      for (int m = 0; m < 8; m++) {
        int r = s * Hh + q + 4 * m;
        float a = sWihB[r * 8 + kcur];
        const float* wr = &sWhh[r * WHH_S];
#pragma unroll
        for (int k = 0; k < Hh; k += 4) {
          float4 w = *(const float4*)&wr[k];
          a = fmaf(w.x, h[k + 0], a);
          a = fmaf(w.y, h[k + 1], a);
          a = fmaf(w.z, h[k + 2], a);
          a = fmaf(w.w, h[k + 3], a);
        }
        accs[s][m] = a;
      }
    }

    // elementwise LSTM cell (fully local: own 8 slots)
    float hnew[8];
#pragma unroll
    for (int m = 0; m < 8; m++) {
      float ig = 1.f / (1.f + expf(-accs[0][m]));
      float fg = 1.f / (1.f + expf(-accs[1][m]));
      float gg = tanhf(accs[2][m]);
      float og = 1.f / (1.f + expf(-accs[3][m]));
      float cc = fg * c[m] + ig * gg;
      c[m] = cc;
      hnew[m] = og * tanhf(cc);
    }
#pragma unroll
    for (int m = 0; m < 8; m++) sHbuf[bb * HBUF_S + q + 4 * m] = hnew[m];

    // head: partial logits over own slots, then quad butterfly-sum
    float lg[8];
#pragma unroll
    for (int p = 0; p < 8; p++) lg[p] = 0.f;
#pragma unroll
    for (int m = 0; m < 8; m++) {
      int j = q + 4 * m;
      float4 w0 = *(const float4*)&sWheadT[j * 8];
      float4 w1 = *(const float4*)&sWheadT[j * 8 + 4];
      lg[0] = fmaf(w0.x, hnew[m], lg[0]);
      lg[1] = fmaf(w0.y, hnew[m], lg[1]);
      lg[2] = fmaf(w0.z, hnew[m], lg[2]);
      lg[3] = fmaf(w0.w, hnew[m], lg[3]);
      lg[4] = fmaf(w1.x, hnew[m], lg[4]);
      lg[5] = fmaf(w1.y, hnew[m], lg[5]);
      lg[6] = fmaf(w1.z, hnew[m], lg[6]);
    }
#pragma unroll
    for (int p = 0; p < Pp; p++) {
      lg[p] += __shfl_xor(lg[p], 1);
      lg[p] += __shfl_xor(lg[p], 2);
      lg[p] += bh[p];
    }

    // gumbel noise + argmax (lane q owns p = q and p = q+4 if < 7)
    const float* ut = gu + (size_t)t * strideT;
    float u1 = ut[q];
    float n1 = -logf(-logf(u1 + 1e-20f) + 1e-20f);
    float bestv = lg[q] + n1;
    int besti = q;
    if (q < 3) {
      float u2 = ut[q + 4];
      float n2 = -logf(-logf(u2 + 1e-20f) + 1e-20f);
      float v2 = lg[q + 4] + n2;
      if (v2 > bestv) { bestv = v2; besti = q + 4; }  // tie -> lower index wins
    }
#pragma unroll
    for (int mask = 1; mask <= 2; mask <<= 1) {
      float ov = __shfl_xor(bestv, mask);
      int   oi = __shfl_xor(besti, mask);
      if (ov > bestv || (ov == bestv && oi < besti)) { bestv = ov; besti = oi; }
    }
    kcur = besti;

    float* lp = outL + (size_t)t * Pp;
    float* sp = outS + (size_t)t * Pp;
    lp[q] = lg[q];
    sp[q] = (besti == q) ? 1.f : 0.f;
    if (q < 3) {
      lp[q + 4] = lg[q + 4];
      sp[q + 4] = (besti == (q + 4)) ? 1.f : 0.f;
    }
  }
}

extern "C" void kernel_launch(void* const* d_in, const int* in_sizes, int n_in,
                              void* d_out, int out_size, void* d_ws, size_t ws_size,
                              hipStream_t stream) {
  const float* h_n     = (const float*)d_in[0];
  const float* c_n     = (const float*)d_in[1];
  const float* noise   = (const float*)d_in[2];
  const float* gumbel  = (const float*)d_in[3];
  const float* W_init  = (const float*)d_in[4];
  const float* b_init  = (const float*)d_in[5];
  const float* W_ih    = (const float*)d_in[6];
  const float* W_hh    = (const float*)d_in[7];
  const float* b_ih    = (const float*)d_in[8];
  const float* b_hh    = (const float*)d_in[9];
  const float* W_head  = (const float*)d_in[10];
  const float* b_head  = (const float*)d_in[11];
  const int*   fut_len = (const int*)d_in[12];

  int B = in_sizes[0] / Hh;  // 32768
  dim3 grid((B + 63) / 64), block(256);
  gen_decoder_kernel<<<grid, block, 0, stream>>>(
      h_n, c_n, noise, gumbel, W_init, b_init, W_ih, W_hh, b_ih, b_hh,
      W_head, b_head, fut_len, (float*)d_out, B);
}